// Round 1
// baseline (147.337 us; speedup 1.0000x reference)
//
#include <hip/hip_runtime.h>

#define B_ 128
#define NIN 1152
#define NOUT 10
#define DDIM 16
#define DK 8
#define TI 9
#define NCH (NIN / TI)            // 128 i-chunks
#define PADX 76                   // 72 floats of x per row + 4 pad (19*16B rows -> conflict-free)
#define SLICES 8
#define SCELLS (B_ * NOUT * DDIM) // 20480

// ---------------------------------------------------------------------------
// Pass kernel: recompute u_hat on the fly for one routing iteration.
// logits: ITER==0 -> 0 (c=0.1); ITER==1 -> u.v0 (vin=vA); ITER==2 -> u.(v0+v1) (vin=vB)
// Accumulates s partial sums into s_part[slice][b][j][d] via atomics.
// Thread decomposition: tid = bg*32 + dg*2 + jh
//   bg in [0,8): 4 b's each (bb);  dg in [0,16): one d;  jh in {0,1}: 5 j's each (jj)
// ---------------------------------------------------------------------------
template<int ITER>
__global__ __launch_bounds__(256, 2)
void caps_pass(const float* __restrict__ x, const float* __restrict__ W,
               const float* __restrict__ vin, float* __restrict__ s_part)
{
    __shared__ float sW[TI * 1280];      // W[i0..i0+9)[10][16][8], 46.1 KB
    __shared__ float sX[32 * PADX];      // x[b0..b0+32)[i0..i0+9)[8], padded, 9.7 KB

    const int ic  = blockIdx.x;          // i-chunk [0,128)
    const int bq  = blockIdx.y;          // b-quarter [0,4)
    const int i0  = ic * TI;
    const int b0  = bq * 32;
    const int tid = threadIdx.x;

    // ---- stage W chunk (fully contiguous) ----
    {
        const float4* Wg  = reinterpret_cast<const float4*>(W + (size_t)i0 * 1280);
        float4*       sWf = reinterpret_cast<float4*>(sW);
        for (int t = tid; t < TI * 1280 / 4; t += 256) sWf[t] = Wg[t];
    }
    // ---- stage x chunk: 32 rows x 72 contiguous floats ----
    for (int t = tid; t < 32 * 18; t += 256) {
        int r = t / 18, c4 = t % 18;
        float4 vx = *reinterpret_cast<const float4*>(
            x + (size_t)(b0 + r) * (NIN * DK) + (size_t)i0 * DK + c4 * 4);
        *reinterpret_cast<float4*>(&sX[r * PADX + c4 * 4]) = vx;
    }
    __syncthreads();

    const int bg = tid >> 5;
    const int dg = (tid >> 1) & 15;
    const int jh = tid & 1;

    // v registers (constant over i) — only for ITER >= 1
    float vr[4][5];
    if (ITER >= 1) {
#pragma unroll
        for (int bb = 0; bb < 4; ++bb)
#pragma unroll
            for (int jj = 0; jj < 5; ++jj)
                vr[bb][jj] = vin[(size_t)(b0 + bg * 4 + bb) * 160 + (jh * 5 + jj) * 16 + dg];
    }

    float s_acc[4][5];
#pragma unroll
    for (int bb = 0; bb < 4; ++bb)
#pragma unroll
        for (int jj = 0; jj < 5; ++jj) s_acc[bb][jj] = 0.f;

#pragma unroll 1
    for (int il = 0; il < TI; ++il) {
        // x for my 4 b's
        float xr[4][8];
#pragma unroll
        for (int bb = 0; bb < 4; ++bb) {
            const float4* px = reinterpret_cast<const float4*>(&sX[(bg * 4 + bb) * PADX + il * 8]);
            float4 a = px[0], b = px[1];
            xr[bb][0] = a.x; xr[bb][1] = a.y; xr[bb][2] = a.z; xr[bb][3] = a.w;
            xr[bb][4] = b.x; xr[bb][5] = b.y; xr[bb][6] = b.z; xr[bb][7] = b.w;
        }
        // u_hat[bb][jj] for my d
        float u[4][5];
#pragma unroll
        for (int jj = 0; jj < 5; ++jj) {
            const int j = jh * 5 + jj;
            const float4* pw = reinterpret_cast<const float4*>(&sW[il * 1280 + j * 128 + dg * 8]);
            float4 w0 = pw[0], w1 = pw[1];
#pragma unroll
            for (int bb = 0; bb < 4; ++bb) {
                float acc = w0.x * xr[bb][0];
                acc = fmaf(w0.y, xr[bb][1], acc);
                acc = fmaf(w0.z, xr[bb][2], acc);
                acc = fmaf(w0.w, xr[bb][3], acc);
                acc = fmaf(w1.x, xr[bb][4], acc);
                acc = fmaf(w1.y, xr[bb][5], acc);
                acc = fmaf(w1.z, xr[bb][6], acc);
                acc = fmaf(w1.w, xr[bb][7], acc);
                u[bb][jj] = acc;
            }
        }

        float c[4][5];
        if (ITER == 0) {
#pragma unroll
            for (int bb = 0; bb < 4; ++bb)
#pragma unroll
                for (int jj = 0; jj < 5; ++jj) c[bb][jj] = 0.1f;
        } else {
            // logit partial = u*v (this d); butterfly-sum over the 16 d lanes (tid bits 1..4)
            float lp[4][5];
#pragma unroll
            for (int bb = 0; bb < 4; ++bb)
#pragma unroll
                for (int jj = 0; jj < 5; ++jj) lp[bb][jj] = u[bb][jj] * vr[bb][jj];
#pragma unroll
            for (int bb = 0; bb < 4; ++bb)
#pragma unroll
                for (int jj = 0; jj < 5; ++jj) {
                    float t = lp[bb][jj];
                    t += __shfl_xor(t, 2, 64);
                    t += __shfl_xor(t, 4, 64);
                    t += __shfl_xor(t, 8, 64);
                    t += __shfl_xor(t, 16, 64);
                    lp[bb][jj] = t;
                }
            // softmax over 10 j (5 local + partner via xor 1)
#pragma unroll
            for (int bb = 0; bb < 4; ++bb) {
                float mx = fmaxf(fmaxf(fmaxf(lp[bb][0], lp[bb][1]),
                                       fmaxf(lp[bb][2], lp[bb][3])), lp[bb][4]);
                mx = fmaxf(mx, __shfl_xor(mx, 1, 64));
                float e0 = __expf(lp[bb][0] - mx);
                float e1 = __expf(lp[bb][1] - mx);
                float e2 = __expf(lp[bb][2] - mx);
                float e3 = __expf(lp[bb][3] - mx);
                float e4 = __expf(lp[bb][4] - mx);
                float sm = e0 + e1 + e2 + e3 + e4;
                sm += __shfl_xor(sm, 1, 64);
                float inv = 1.0f / sm;
                c[bb][0] = e0 * inv; c[bb][1] = e1 * inv; c[bb][2] = e2 * inv;
                c[bb][3] = e3 * inv; c[bb][4] = e4 * inv;
            }
        }
        // s += c * u
#pragma unroll
        for (int bb = 0; bb < 4; ++bb)
#pragma unroll
            for (int jj = 0; jj < 5; ++jj)
                s_acc[bb][jj] = fmaf(c[bb][jj], u[bb][jj], s_acc[bb][jj]);
    }

    // epilogue: atomic accumulate into contention slice (ic & 7)
    float* sp = s_part + (size_t)(ic & (SLICES - 1)) * SCELLS;
#pragma unroll
    for (int bb = 0; bb < 4; ++bb)
#pragma unroll
        for (int jj = 0; jj < 5; ++jj)
            atomicAdd(&sp[(b0 + bg * 4 + bb) * 160 + (jh * 5 + jj) * 16 + dg],
                      s_acc[bb][jj]);
}

// ---------------------------------------------------------------------------
// Squash kernel: sum 8 slices + bias, squash along d (16 lanes/row shuffle),
// write v; re-zero slices for the next pass.
// MODE 0: v_out = squash(s)            (writes vA)
// MODE 1: v_out = v_prev + squash(s)   (writes vB = v0+v1)
// MODE 2: v_out = squash(s)            (final -> d_out, no re-zero)
// ---------------------------------------------------------------------------
template<int MODE>
__global__ __launch_bounds__(256)
void caps_squash(float* __restrict__ s_part, const float* __restrict__ bias,
                 const float* __restrict__ v_prev, float* __restrict__ v_out)
{
    const int gid = blockIdx.x * 256 + threadIdx.x;   // [0, 20480)
    const int row = gid >> 4;                         // b*10 + j
    const int d   = gid & 15;
    const int j   = row % NOUT;

    float sd = bias[j * 16 + d];
#pragma unroll
    for (int g = 0; g < SLICES; ++g) sd += s_part[g * SCELLS + gid];
    if (MODE != 2) {
#pragma unroll
        for (int g = 0; g < SLICES; ++g) s_part[g * SCELLS + gid] = 0.f;
    }

    float sq = sd * sd;
    sq += __shfl_xor(sq, 1, 64);
    sq += __shfl_xor(sq, 2, 64);
    sq += __shfl_xor(sq, 4, 64);
    sq += __shfl_xor(sq, 8, 64);

    float scale = sq / ((1.0f + sq) * sqrtf(sq + 1e-7f));
    float v = sd * scale;

    if (MODE == 1) v = v_prev[gid] + v;
    v_out[gid] = v;
}

extern "C" void kernel_launch(void* const* d_in, const int* in_sizes, int n_in,
                              void* d_out, int out_size, void* d_ws, size_t ws_size,
                              hipStream_t stream)
{
    const float* x    = (const float*)d_in[0];
    const float* W    = (const float*)d_in[1];
    const float* bias = (const float*)d_in[2];
    float* out = (float*)d_out;

    float* s_part = (float*)d_ws;                 // 8 * 20480 floats = 655 KB
    float* vA     = s_part + SLICES * SCELLS;     // 20480 floats (v0)
    float* vB     = vA + SCELLS;                  // 20480 floats (v0+v1)

    hipMemsetAsync(s_part, 0, (size_t)SLICES * SCELLS * sizeof(float), stream);

    dim3 pgrid(NCH, 4);
    caps_pass<0><<<pgrid, 256, 0, stream>>>(x, W, nullptr, s_part);
    caps_squash<0><<<SCELLS / 256, 256, 0, stream>>>(s_part, bias, nullptr, vA);
    caps_pass<1><<<pgrid, 256, 0, stream>>>(x, W, vA, s_part);
    caps_squash<1><<<SCELLS / 256, 256, 0, stream>>>(s_part, bias, vA, vB);
    caps_pass<2><<<pgrid, 256, 0, stream>>>(x, W, vB, s_part);
    caps_squash<2><<<SCELLS / 256, 256, 0, stream>>>(s_part, bias, nullptr, out);
}